// Round 1
// 1999.599 us; speedup vs baseline: 1.7471x; 1.7471x over previous
//
#include <hip/hip_runtime.h>
#include <cstddef>
#include <cstdint>

// ---------------- constants ----------------
#define BB 8
#define SS 256
#define WW 8
#define DD 512
#define HH 8
#define DKK 64
#define DFFF 2048
#define LL 6
#define NPAIR 32385            // (S-1)(S-2)/2 with S=256 -> 255*254/2
#define SPAN_TOTAL 132648960LL // 8*32385*512

typedef __attribute__((ext_vector_type(8))) short bf16x8;
typedef __attribute__((ext_vector_type(4))) float f32x4;
typedef unsigned short u16;

// ---------------- device helpers ----------------
__device__ __forceinline__ float sigf(float x) { return 1.f / (1.f + __expf(-x)); }
__device__ __forceinline__ float tanh_fast(float x) { return 1.f - 2.f / (__expf(2.f * x) + 1.f); }

// split fp32 v into bf16 hi + bf16 lo (truncation; v ~= hi + lo to ~2^-15 rel)
__device__ __forceinline__ void split2(float v, u16& h, u16& l) {
  unsigned u = __float_as_uint(v);
  h = (u16)(u >> 16);
  float fl = v - __uint_as_float(u & 0xffff0000u);
  l = (u16)(__float_as_uint(fl) >> 16);
}

__device__ __forceinline__ float block_sum(float v) {
  __shared__ float sb[8];
  #pragma unroll
  for (int o = 32; o > 0; o >>= 1) v += __shfl_down(v, o, 64);
  __syncthreads();
  if ((threadIdx.x & 63) == 0) sb[threadIdx.x >> 6] = v;
  __syncthreads();
  float t = 0.f;
  const int nw = blockDim.x >> 6;
  for (int i = 0; i < nw; ++i) t += sb[i];
  return t;
}

__device__ __forceinline__ float block_max(float v) {
  __shared__ float sb[8];
  #pragma unroll
  for (int o = 32; o > 0; o >>= 1) v = fmaxf(v, __shfl_down(v, o, 64));
  __syncthreads();
  if ((threadIdx.x & 63) == 0) sb[threadIdx.x >> 6] = v;
  __syncthreads();
  float t = -3.4e38f;
  const int nw = blockDim.x >> 6;
  for (int i = 0; i < nw; ++i) t = fmaxf(t, sb[i]);
  return t;
}

// ---------------- char BiLSTM ----------------
__global__ __launch_bounds__(256) void lstm_k(
    const int* __restrict__ char_idxs, const float* __restrict__ char_emb,
    const float* __restrict__ Wih_f, const float* __restrict__ Whh_f, const float* __restrict__ b_f,
    const float* __restrict__ Wih_b, const float* __restrict__ Whh_b, const float* __restrict__ b_b,
    float* __restrict__ hf, float* __restrict__ hb) {
  const int dir = blockIdx.y;
  const float* __restrict__ Wih = dir ? Wih_b : Wih_f;
  const float* __restrict__ Whh = dir ? Whh_b : Whh_f;
  const float* __restrict__ bv = dir ? b_b : b_f;
  float* __restrict__ dst = dir ? hb : hf;
  const int n0 = blockIdx.x * 8;
  const int tid = threadIdx.x;

  __shared__ float hs[150][8];
  __shared__ float cs[150][8];
  __shared__ float gs[8][600];
  __shared__ float xs[64][8];

  for (int i = tid; i < 1200; i += 256) { hs[i >> 3][i & 7] = 0.f; cs[i >> 3][i & 7] = 0.f; }

  const int j0 = tid, j1 = tid + 256, j2 = tid + 512;
  const bool a2 = (j2 < 600);
  const float bias0 = bv[j0], bias1 = bv[j1], bias2 = a2 ? bv[j2] : 0.f;
  __syncthreads();

  for (int st = 0; st < 8; ++st) {
    const int t = dir ? (7 - st) : st;
    for (int i = tid; i < 512; i += 256) {
      const int s = i >> 6, kk = i & 63;
      const int ci = char_idxs[(n0 + s) * 8 + t];
      xs[kk][s] = char_emb[ci * 64 + kk];
    }
    __syncthreads();

    float acc0[8], acc1[8], acc2[8];
    #pragma unroll
    for (int s = 0; s < 8; ++s) { acc0[s] = bias0; acc1[s] = bias1; acc2[s] = bias2; }

    for (int k = 0; k < 64; ++k) {
      const float w0 = Wih[k * 600 + j0];
      const float w1 = Wih[k * 600 + j1];
      const float w2 = a2 ? Wih[k * 600 + j2] : 0.f;
      const float4 xa = *(const float4*)&xs[k][0];
      const float4 xb4 = *(const float4*)&xs[k][4];
      const float xv[8] = {xa.x, xa.y, xa.z, xa.w, xb4.x, xb4.y, xb4.z, xb4.w};
      #pragma unroll
      for (int s = 0; s < 8; ++s) { acc0[s] += w0 * xv[s]; acc1[s] += w1 * xv[s]; acc2[s] += w2 * xv[s]; }
    }
    for (int k = 0; k < 150; ++k) {
      const float w0 = Whh[k * 600 + j0];
      const float w1 = Whh[k * 600 + j1];
      const float w2 = a2 ? Whh[k * 600 + j2] : 0.f;
      const float4 ha = *(const float4*)&hs[k][0];
      const float4 hb4 = *(const float4*)&hs[k][4];
      const float hv[8] = {ha.x, ha.y, ha.z, ha.w, hb4.x, hb4.y, hb4.z, hb4.w};
      #pragma unroll
      for (int s = 0; s < 8; ++s) { acc0[s] += w0 * hv[s]; acc1[s] += w1 * hv[s]; acc2[s] += w2 * hv[s]; }
    }
    #pragma unroll
    for (int s = 0; s < 8; ++s) {
      gs[s][j0] = acc0[s];
      gs[s][j1] = acc1[s];
      if (a2) gs[s][j2] = acc2[s];
    }
    __syncthreads();
    for (int i = tid; i < 1200; i += 256) {
      const int u = i >> 3, s = i & 7;
      const float ig = sigf(gs[s][u]);
      const float fg = sigf(gs[s][150 + u]);
      const float gg = tanh_fast(gs[s][300 + u]);
      const float og = sigf(gs[s][450 + u]);
      const float cc = fg * cs[u][s] + ig * gg;
      cs[u][s] = cc;
      hs[u][s] = og * tanh_fast(cc);
    }
    __syncthreads();
  }
  for (int i = tid; i < 1200; i += 256) {
    const int u = i >> 3, s = i & 7;
    dst[(size_t)(n0 + s) * 150 + u] = hs[u][s];
  }
}

// ---------------- embedding + concat + LN0 (+ bf16 hi/lo split) ----------------
__global__ __launch_bounds__(512) void embed_ln0_k(
    const int* __restrict__ word_idxs,
    const float* __restrict__ ext_emb, const float* __restrict__ word_emb,
    const float* __restrict__ hf, const float* __restrict__ hb,
    const float* __restrict__ pos_emb,
    const float* __restrict__ g, const float* __restrict__ be,
    float* __restrict__ x, u16* __restrict__ oh, u16* __restrict__ ol) {
  const int n = blockIdx.x;
  const int s = n & 255;
  const int c = threadIdx.x;
  const int w = word_idxs[n];
  const int wid = (w >= 32000) ? 1 : w;
  const int pos = (w != 0) ? (s + 1) : 0;
  float v;
  if (c < 300) {
    v = ext_emb[(size_t)w * 300 + c] + word_emb[(size_t)wid * 300 + c];
    v += (c < 150) ? hf[(size_t)n * 150 + c] : hb[(size_t)n * 150 + (c - 150)];
  } else {
    v = pos_emb[(size_t)pos * 212 + (c - 300)];
  }
  const float mean = block_sum(v) * (1.f / 512.f);
  const float d = v - mean;
  const float var = block_sum(d * d) * (1.f / 512.f);
  const float r = d * rsqrtf(var + 1e-5f) * g[c] + be[c];
  const size_t idx = (size_t)n * 512 + c;
  x[idx] = r;
  u16 h, l;
  split2(r, h, l);
  oh[idx] = h;
  ol[idx] = l;
}

// ---------------- residual(+partials,+bias) + LayerNorm (+ split) ----------------
__global__ __launch_bounds__(512) void ln_k(
    const float* __restrict__ inp, int nparts, long long pstride,
    const float* __restrict__ res, const float* __restrict__ bias,
    const float* __restrict__ g, const float* __restrict__ be,
    float* __restrict__ out, u16* __restrict__ oh, u16* __restrict__ ol) {
  const int n = blockIdx.x;
  const int c = threadIdx.x;
  const size_t idx = (size_t)n * 512 + c;
  float v = inp[idx];
  for (int p = 1; p < nparts; ++p) v += inp[(size_t)p * pstride + idx];
  v += res[idx];
  if (bias) v += bias[c];
  const float mean = block_sum(v) * (1.f / 512.f);
  const float d = v - mean;
  const float var = block_sum(d * d) * (1.f / 512.f);
  const float r = d * rsqrtf(var + 1e-5f) * g[c] + be[c];
  out[idx] = r;
  u16 h, l;
  split2(r, h, l);
  oh[idx] = h;
  ol[idx] = l;
}

// ---------------- fp32 -> bf16 hi/lo elementwise split ----------------
__global__ __launch_bounds__(256) void split_k(const float* __restrict__ in,
                                               u16* __restrict__ h, u16* __restrict__ l, int n4) {
  const int i = blockIdx.x * 256 + threadIdx.x;
  if (i >= n4) return;
  const float4 v = ((const float4*)in)[i];
  ushort4 hh, ll;
  split2(v.x, hh.x, ll.x);
  split2(v.y, hh.y, ll.y);
  split2(v.z, hh.z, ll.z);
  split2(v.w, hh.w, ll.w);
  ((ushort4*)h)[i] = hh;
  ((ushort4*)l)[i] = ll;
}

// ---------------- weight transpose + bf16 hi/lo split ----------------
// src: [K][N] fp32, z-strided; dst: [N][K] bf16 hi/lo
__global__ __launch_bounds__(256) void wconv_k(
    const float* __restrict__ src, u16* __restrict__ dh, u16* __restrict__ dl,
    int K, int N, long long sS, long long sD) {
  const int z = blockIdx.z;
  const float* __restrict__ s = src + (size_t)z * sS;
  u16* __restrict__ oh = dh + (size_t)z * sD;
  u16* __restrict__ ol = dl + (size_t)z * sD;
  const int k0 = blockIdx.y << 6, n0 = blockIdx.x << 6;
  __shared__ float t[64][65];
  for (int i = threadIdx.x; i < 4096; i += 256) {
    const int r = i >> 6, c = i & 63;
    t[r][c] = s[(size_t)(k0 + r) * N + n0 + c];
  }
  __syncthreads();
  for (int i = threadIdx.x; i < 4096; i += 256) {
    const int nn = i >> 6, kk = i & 63;
    u16 h, l;
    split2(t[kk][nn], h, l);
    const size_t o = (size_t)(n0 + nn) * K + k0 + kk;
    oh[o] = h;
    ol[o] = l;
  }
}

// ---------------- bf16x3 MFMA GEMM ----------------
// C[M][N] = (Ah+Al)[M][K] @ (Bh+Bl)^T where Bh/Bl stored [N][K] (k-contiguous).
// 64x64 tile, 1 wave/block, BK=32, double-buffered global_load_lds staging.
// OMODE 0: C fp32 (+opt bias), batched by bz (B += bz*sB, C += bz*sC)
// OMODE 1: C fp32 partials at C + z*sC (split-K, summed later in ln_k)
// OMODE 2: bf16 hi/lo out (Ch/Cl), +bias, optional relu
template <int KSPLIT, int OMODE, int RELU>
__global__ __launch_bounds__(64) void mgemm_k(
    const u16* __restrict__ Agh, const u16* __restrict__ Agl,
    const u16* __restrict__ Bgh, const u16* __restrict__ Bgl,
    const float* __restrict__ bias,
    float* __restrict__ C, u16* __restrict__ Ch, u16* __restrict__ Cl,
    int N, int K, long long sB, long long sC) {
  const int z = blockIdx.z;
  const int bz = z / KSPLIT;
  const int ks = z - bz * KSPLIT;
  const int m0 = blockIdx.y << 6;
  const int n0 = blockIdx.x << 6;
  const int ln = threadIdx.x;

  __shared__ __align__(16) u16 SA[2][2][64][32]; // [buf][hi/lo][row][k]
  __shared__ __align__(16) u16 SB[2][2][64][32];

  const u16* __restrict__ Bh = Bgh + (size_t)bz * sB;
  const u16* __restrict__ Bl = Bgl + (size_t)bz * sB;

  const int Kc = K / KSPLIT;
  const int kbeg = ks * Kc;
  const int nsteps = Kc >> 5;

  const int srow = ln >> 2;       // staging: row within 16-row chunk
  const int sk = (ln & 3) << 3;   // staging: k element offset (0,8,16,24)

  auto stage = [&](const u16* __restrict__ src, int row0, int kt, u16* lb) {
    #pragma unroll
    for (int c = 0; c < 4; ++c) {
      const u16* g = src + (size_t)(row0 + (c << 4) + srow) * K + kt + sk;
      __builtin_amdgcn_global_load_lds(
          (__attribute__((address_space(1))) void*)g,
          (__attribute__((address_space(3))) void*)(lb + (c << 9)), 16, 0, 0);
    }
  };

  f32x4 acc[4][4];
  #pragma unroll
  for (int i = 0; i < 4; ++i)
    #pragma unroll
    for (int j = 0; j < 4; ++j)
      #pragma unroll
      for (int r = 0; r < 4; ++r) acc[i][j][r] = 0.f;

  // prologue: stage buffer 0
  stage(Agh, m0, kbeg, &SA[0][0][0][0]);
  stage(Agl, m0, kbeg, &SA[0][1][0][0]);
  stage(Bh, n0, kbeg, &SB[0][0][0][0]);
  stage(Bl, n0, kbeg, &SB[0][1][0][0]);

  const int lr = ln & 15;
  const int kq = (ln >> 4) << 3;

  int kt = kbeg;
  for (int t = 0; t < nsteps; ++t, kt += 32) {
    const int cb = t & 1, nb2 = cb ^ 1;
    // all prior ds_reads retired before we overwrite any LDS
    asm volatile("s_waitcnt lgkmcnt(0)" ::: "memory");
    __builtin_amdgcn_sched_barrier(0);
    if (t + 1 < nsteps) {
      stage(Agh, m0, kt + 32, &SA[nb2][0][0][0]);
      stage(Agl, m0, kt + 32, &SA[nb2][1][0][0]);
      stage(Bh, n0, kt + 32, &SB[nb2][0][0][0]);
      stage(Bl, n0, kt + 32, &SB[nb2][1][0][0]);
      asm volatile("s_waitcnt vmcnt(16)" ::: "memory"); // current buf landed, next 16 in flight
    } else {
      asm volatile("s_waitcnt vmcnt(0)" ::: "memory");
    }
    __builtin_amdgcn_sched_barrier(0);

    bf16x8 fa_h[4], fa_l[4], fb_h[4], fb_l[4];
    #pragma unroll
    for (int m = 0; m < 4; ++m) {
      fa_h[m] = *(const bf16x8*)&SA[cb][0][(m << 4) + lr][kq];
      fa_l[m] = *(const bf16x8*)&SA[cb][1][(m << 4) + lr][kq];
    }
    #pragma unroll
    for (int n = 0; n < 4; ++n) {
      fb_h[n] = *(const bf16x8*)&SB[cb][0][(n << 4) + lr][kq];
      fb_l[n] = *(const bf16x8*)&SB[cb][1][(n << 4) + lr][kq];
    }
    #pragma unroll
    for (int m = 0; m < 4; ++m)
      #pragma unroll
      for (int n = 0; n < 4; ++n) {
        acc[m][n] = __builtin_amdgcn_mfma_f32_16x16x32_bf16(fa_h[m], fb_h[n], acc[m][n], 0, 0, 0);
        acc[m][n] = __builtin_amdgcn_mfma_f32_16x16x32_bf16(fa_l[m], fb_h[n], acc[m][n], 0, 0, 0);
        acc[m][n] = __builtin_amdgcn_mfma_f32_16x16x32_bf16(fa_h[m], fb_l[n], acc[m][n], 0, 0, 0);
      }
  }

  const int crow = (ln >> 4) << 2;
  const int ccol = ln & 15;
  #pragma unroll
  for (int m = 0; m < 4; ++m)
    #pragma unroll
    for (int n = 0; n < 4; ++n)
      #pragma unroll
      for (int r = 0; r < 4; ++r) {
        const int row = m0 + (m << 4) + crow + r;
        const int col = n0 + (n << 4) + ccol;
        float v = acc[m][n][r];
        if (OMODE == 0) {
          if (bias) v += bias[col];
          C[(size_t)bz * sC + (size_t)row * N + col] = v;
        } else if (OMODE == 1) {
          C[(size_t)z * sC + (size_t)row * N + col] = v;
        } else {
          v += bias[col];
          if (RELU) v = fmaxf(v, 0.f);
          u16 h, l;
          split2(v, h, l);
          Ch[(size_t)row * N + col] = h;
          Cl[(size_t)row * N + col] = l;
        }
      }
}

// ---------------- generic batched tiled fp32 GEMM (attention path) ----------------
__global__ __launch_bounds__(256) void gemm_k(
    const float* __restrict__ A, const float* __restrict__ B,
    const float* __restrict__ bias, float* __restrict__ C,
    int K, int lda, int ldb, int ldc,
    long long sA1, long long sA2, long long sB1, long long sB2,
    long long sC1, long long sC2, int bdiv, int transB, int relu) {
  __shared__ float As[16][64];
  __shared__ float Bs[16][64];
  const int bz = blockIdx.z;
  const int b1 = bz / bdiv, b2 = bz % bdiv;
  const float* __restrict__ Ab = A + b1 * sA1 + b2 * sA2;
  const float* __restrict__ Bb = B + b1 * sB1 + b2 * sB2;
  float* __restrict__ Cb = C + b1 * sC1 + b2 * sC2;
  const int n0 = blockIdx.x * 64, m0 = blockIdx.y * 64;
  const int tid = threadIdx.x;
  const int tx = tid & 15, ty = tid >> 4;
  const int lm = tid >> 2, lk4 = (tid & 3) << 2;
  const int lbk = tid >> 4, lbn4 = (tid & 15) << 2;

  float acc[4][4] = {};
  for (int kt = 0; kt < K; kt += 16) {
    const float4 av = *(const float4*)(Ab + (size_t)(m0 + lm) * lda + kt + lk4);
    float4 bv4;
    if (!transB) bv4 = *(const float4*)(Bb + (size_t)(kt + lbk) * ldb + n0 + lbn4);
    else         bv4 = *(const float4*)(Bb + (size_t)(n0 + lm) * ldb + kt + lk4);
    __syncthreads();
    As[lk4 + 0][lm] = av.x; As[lk4 + 1][lm] = av.y; As[lk4 + 2][lm] = av.z; As[lk4 + 3][lm] = av.w;
    if (!transB) { *(float4*)&Bs[lbk][lbn4] = bv4; }
    else { Bs[lk4 + 0][lm] = bv4.x; Bs[lk4 + 1][lm] = bv4.y; Bs[lk4 + 2][lm] = bv4.z; Bs[lk4 + 3][lm] = bv4.w; }
    __syncthreads();
    #pragma unroll
    for (int k = 0; k < 16; ++k) {
      const float4 a4 = *(const float4*)&As[k][ty << 2];
      const float4 b4 = *(const float4*)&Bs[k][tx << 2];
      const float ar[4] = {a4.x, a4.y, a4.z, a4.w};
      const float br[4] = {b4.x, b4.y, b4.z, b4.w};
      #pragma unroll
      for (int i = 0; i < 4; ++i)
        #pragma unroll
        for (int j = 0; j < 4; ++j)
          acc[i][j] += ar[i] * br[j];
    }
  }
  float bvv[4] = {0.f, 0.f, 0.f, 0.f};
  if (bias) {
    #pragma unroll
    for (int j = 0; j < 4; ++j) bvv[j] = bias[n0 + (tx << 2) + j];
  }
  #pragma unroll
  for (int i = 0; i < 4; ++i) {
    float vals[4];
    #pragma unroll
    for (int j = 0; j < 4; ++j) {
      float vv = acc[i][j] + bvv[j];
      if (relu) vv = fmaxf(vv, 0.f);
      vals[j] = vv;
    }
    float4 o;
    o.x = vals[0]; o.y = vals[1]; o.z = vals[2]; o.w = vals[3];
    *(float4*)(Cb + (size_t)(m0 + (ty << 2) + i) * ldc + n0 + (tx << 2)) = o;
  }
}

// ---------------- softmax over keys with mask bias ----------------
__global__ __launch_bounds__(256) void softmax_k(float* __restrict__ probs,
                                                 const int* __restrict__ word) {
  const int row = blockIdx.x;
  const int b = row >> 11;
  float* p = probs + (size_t)row * 256;
  const int j = threadIdx.x;
  const float s = p[j] * 0.125f + ((word[b * 256 + j] != 0) ? 0.f : -1e9f);
  const float m = block_max(s);
  const float e = __expf(s - m);
  const float t = block_sum(e);
  p[j] = e / t;
}

// ---------------- span epilogue ----------------
__device__ __forceinline__ int pair_off(int p) { return (509 * p - p * p) >> 1; }

__global__ __launch_bounds__(256) void span_k(const float* __restrict__ x,
                                              const int* __restrict__ word,
                                              float* __restrict__ out) {
  const int t = blockIdx.x;
  const int b = blockIdx.y;
  int p = (int)((509.0f - sqrtf(259081.0f - 8.0f * (float)t)) * 0.5f);
  p = max(0, min(p, 253));
  while (p < 253 && pair_off(p + 1) <= t) ++p;
  while (p > 0 && pair_off(p) > t) --p;
  const int q = p + 1 + (t - pair_off(p));
  const int w = word[b * 256 + q];
  const float valid = (w != 0 && w != 2) ? 1.f : 0.f;
  const float* xb = x + (size_t)b * 256 * 512;
  const int c = threadIdx.x;
  const float fwd = xb[(size_t)q * 512 + 2 * c] - xb[(size_t)p * 512 + 2 * c];
  const float bwd = xb[(size_t)(p + 1) * 512 + 2 * c + 1] - xb[(size_t)(q + 1) * 512 + 2 * c + 1];
  float* o = out + ((size_t)b * NPAIR + t) * 512;
  o[c] = fwd * valid;
  o[256 + c] = bwd * valid;
}

// ---------------- sentence lengths ----------------
__global__ __launch_bounds__(256) void lens_k(const int* __restrict__ word,
                                              float* __restrict__ out) {
  const int b = blockIdx.x;
  const float m = (word[b * 256 + threadIdx.x] != 0) ? 1.f : 0.f;
  const float tot = block_sum(m);
  if (threadIdx.x == 0) out[b] = tot - 2.f;
}

// ---------------- host side ----------------
static inline void gemm(hipStream_t st, const float* A, const float* B, const float* bias,
                        float* C, int M, int N, int K, int lda, int ldb, int ldc,
                        long long sA1, long long sA2, long long sB1, long long sB2,
                        long long sC1, long long sC2, int nb, int bdiv, int transB, int relu) {
  gemm_k<<<dim3(N / 64, M / 64, nb), 256, 0, st>>>(A, B, bias, C, K, lda, ldb, ldc,
                                                   sA1, sA2, sB1, sB2, sC1, sC2, bdiv, transB, relu);
}

extern "C" void kernel_launch(void* const* d_in, const int* in_sizes, int n_in,
                              void* d_out, int out_size, void* d_ws, size_t ws_size,
                              hipStream_t stream) {
  const int* word_idxs = (const int*)d_in[0];
  const int* char_idxs = (const int*)d_in[1];
  const float* ext_emb = (const float*)d_in[2];
  const float* word_emb = (const float*)d_in[3];
  const float* char_emb = (const float*)d_in[4];
  const float* Wih_f = (const float*)d_in[5];
  const float* Whh_f = (const float*)d_in[6];
  const float* b_f = (const float*)d_in[7];
  const float* Wih_b = (const float*)d_in[8];
  const float* Whh_b = (const float*)d_in[9];
  const float* b_b = (const float*)d_in[10];
  const float* pos_emb = (const float*)d_in[11];
  const float* ln0_g = (const float*)d_in[12];
  const float* ln0_b = (const float*)d_in[13];
  const float* Wq_a = (const float*)d_in[14];
  const float* Wk_a = (const float*)d_in[15];
  const float* Wv_a = (const float*)d_in[16];
  const float* Wo_a = (const float*)d_in[17];
  const float* ln1g = (const float*)d_in[18];
  const float* ln1b = (const float*)d_in[19];
  const float* W1_a = (const float*)d_in[20];
  const float* b1_a = (const float*)d_in[21];
  const float* W2_a = (const float*)d_in[22];
  const float* b2_a = (const float*)d_in[23];
  const float* ln2g = (const float*)d_in[24];
  const float* ln2b = (const float*)d_in[25];

  float* out = (float*)d_out;
  float* p = (float*)d_ws;
  float* hf = p;   p += 307200;
  float* hb = p;   p += 307200;
  float* x = p;    p += 1048576;
  float* qkv = p;  p += 3145728;            // qb | kb | vb
  float* att = p;  p += 1048576;
  float* tmp = p;  p += 4194304;            // up to 4 split-K partials
  float* prb = p;  p += 4194304;

  u16* us = (u16*)p;
  u16* xh = us;      us += 1048576;
  u16* xl = us;      us += 1048576;
  u16* ah = us;      us += 1048576;
  u16* al = us;      us += 1048576;
  u16* fhh = us;     us += 4194304;
  u16* fhl = us;     us += 4194304;
  u16* qkvT_h = us;  us += 4718592;         // 6 layers x [3][512][512]
  u16* qkvT_l = us;  us += 4718592;
  u16* woT_h = us;   us += 1572864;         // 6 x [512][512]
  u16* woT_l = us;   us += 1572864;
  u16* w1T_h = us;   us += 6291456;         // 6 x [2048][512]
  u16* w1T_l = us;   us += 6291456;
  u16* w2T_h = us;   us += 6291456;         // 6 x [512][2048]
  u16* w2T_l = us;   us += 6291456;

  float* qb = qkv;
  float* kb = qkv + 1048576;
  float* vb = qkv + 2097152;

  // one-time weight transpose + bf16 hi/lo split (all 6 layers per launch)
  wconv_k<<<dim3(8, 8, 6), 256, 0, stream>>>(Wq_a, qkvT_h, qkvT_l, 512, 512, 262144LL, 786432LL);
  wconv_k<<<dim3(8, 8, 6), 256, 0, stream>>>(Wk_a, qkvT_h + 262144, qkvT_l + 262144, 512, 512, 262144LL, 786432LL);
  wconv_k<<<dim3(8, 8, 6), 256, 0, stream>>>(Wv_a, qkvT_h + 524288, qkvT_l + 524288, 512, 512, 262144LL, 786432LL);
  wconv_k<<<dim3(8, 8, 6), 256, 0, stream>>>(Wo_a, woT_h, woT_l, 512, 512, 262144LL, 262144LL);
  wconv_k<<<dim3(32, 8, 6), 256, 0, stream>>>(W1_a, w1T_h, w1T_l, 512, 2048, 1048576LL, 1048576LL);
  wconv_k<<<dim3(8, 32, 6), 256, 0, stream>>>(W2_a, w2T_h, w2T_l, 2048, 512, 1048576LL, 1048576LL);

  lstm_k<<<dim3(256, 2), 256, 0, stream>>>(char_idxs, char_emb, Wih_f, Whh_f, b_f,
                                           Wih_b, Whh_b, b_b, hf, hb);
  embed_ln0_k<<<2048, 512, 0, stream>>>(word_idxs, ext_emb, word_emb, hf, hb,
                                        pos_emb, ln0_g, ln0_b, x, xh, xl);

  for (int l = 0; l < LL; ++l) {
    const u16* wqh = qkvT_h + (size_t)l * 786432;
    const u16* wql = qkvT_l + (size_t)l * 786432;
    const u16* woh = woT_h + (size_t)l * 262144;
    const u16* wol = woT_l + (size_t)l * 262144;
    const u16* w1h = w1T_h + (size_t)l * 1048576;
    const u16* w1l = w1T_l + (size_t)l * 1048576;
    const u16* w2h = w2T_h + (size_t)l * 1048576;
    const u16* w2l = w2T_l + (size_t)l * 1048576;

    // Q,K,V in one batched MFMA GEMM (z = 0..2)
    mgemm_k<1, 0, 0><<<dim3(8, 32, 3), 64, 0, stream>>>(
        xh, xl, wqh, wql, nullptr, qkv, nullptr, nullptr, 512, 512, 262144LL, 1048576LL);
    // scores = Q_h @ K_h^T per (b,h)  (fp32 path)
    gemm(stream, qb, kb, nullptr, prb, 256, 256, 64, 512, 512, 256,
         131072LL, 64LL, 131072LL, 64LL, 524288LL, 65536LL, 64, 8, 1, 0);
    softmax_k<<<16384, 256, 0, stream>>>(prb, word_idxs);
    // att = P @ V_h  (fp32 path)
    gemm(stream, prb, vb, nullptr, att, 256, 64, 256, 256, 512, 512,
         524288LL, 65536LL, 131072LL, 64LL, 131072LL, 64LL, 64, 8, 0, 0);
    split_k<<<1024, 256, 0, stream>>>(att, ah, al, 262144);
    // O projection, split-K=2 partials into tmp[0..1]
    mgemm_k<2, 1, 0><<<dim3(8, 32, 2), 64, 0, stream>>>(
        ah, al, woh, wol, nullptr, tmp, nullptr, nullptr, 512, 512, 0LL, 1048576LL);
    ln_k<<<2048, 512, 0, stream>>>(tmp, 2, 1048576LL, x, nullptr,
                                   ln1g + l * 512, ln1b + l * 512, x, xh, xl);
    // FFN1 (+bias,+relu) -> bf16 hi/lo directly
    mgemm_k<1, 2, 1><<<dim3(32, 32, 1), 64, 0, stream>>>(
        xh, xl, w1h, w1l, b1_a + l * 2048, nullptr, fhh, fhl, 2048, 512, 0LL, 0LL);
    // FFN2, split-K=4 partials into tmp[0..3] (bias folded into ln_k)
    mgemm_k<4, 1, 0><<<dim3(8, 32, 4), 64, 0, stream>>>(
        fhh, fhl, w2h, w2l, nullptr, tmp, nullptr, nullptr, 512, 2048, 0LL, 1048576LL);
    ln_k<<<2048, 512, 0, stream>>>(tmp, 4, 1048576LL, x, b2_a + l * 512,
                                   ln2g + l * 512, ln2b + l * 512, x, xh, xl);
  }

  span_k<<<dim3(NPAIR, 8), 256, 0, stream>>>(x, word_idxs, out);
  lens_k<<<8, 256, 0, stream>>>(word_idxs, out + (size_t)SPAN_TOTAL);
}